// Round 7
// baseline (116.086 us; speedup 1.0000x reference)
//
#include <hip/hip_runtime.h>

#define SCALE 0.125f

typedef unsigned short ushort_t;
typedef unsigned short ushortx8 __attribute__((ext_vector_type(8)));
typedef unsigned short ushortx4 __attribute__((ext_vector_type(4)));
typedef short bf16x8 __attribute__((ext_vector_type(8)));
typedef float f32x4 __attribute__((ext_vector_type(4)));

__device__ inline ushort_t f2bf(float f) {
  unsigned int u = __float_as_uint(f);
  u += 0x7FFFu + ((u >> 16) & 1u);
  return (ushort_t)(u >> 16);
}
__device__ inline float bf2f(ushort_t u) {
  return __uint_as_float(((unsigned int)u) << 16);
}

// ---------------- fused prep: x cvt + 4 weight transposes ----------------
__global__ __launch_bounds__(256) void prep_kernel(
    const float* __restrict__ x, const float* __restrict__ Wq, const float* __restrict__ Wk,
    const float* __restrict__ Wv, const float* __restrict__ Wo,
    ushort_t* __restrict__ x_bf, ushort_t* __restrict__ wqkv_t, ushort_t* __restrict__ wo_t)
{
  __shared__ float t[64][65];
  int bid = blockIdx.x;
  const int tid = threadIdx.x;
  if (bid < 2048) {
    int idx = (bid * 256 + tid) * 4;
    if (idx < 2048 * 1024) {
      float4 f = *(const float4*)(x + idx);
      ushortx4 o = { f2bf(f.x), f2bf(f.y), f2bf(f.z), f2bf(f.w) };
      *(ushortx4*)(x_bf + idx) = o;
    }
    return;
  }
  bid -= 2048;
  const float* src; int C; ushort_t* dst; int row_off, cb, kb;
  if (bid < 256)      { src = Wq; C = 1024; dst = wqkv_t; row_off = 0;    cb = bid & 15; kb = bid >> 4; }
  else if (bid < 320) { int j = bid - 256; src = Wk; C = 256; dst = wqkv_t; row_off = 1024; cb = j & 3; kb = j >> 2; }
  else if (bid < 384) { int j = bid - 320; src = Wv; C = 256; dst = wqkv_t; row_off = 1280; cb = j & 3; kb = j >> 2; }
  else                { int j = bid - 384; src = Wo; C = 1024; dst = wo_t; row_off = 0;    cb = j & 15; kb = j >> 4; }
  const int c0 = cb * 64, k0 = kb * 64;
  const int c = tid & 63, r4 = tid >> 6;
  for (int rr = r4; rr < 64; rr += 4)
    t[c][rr] = src[(size_t)(k0 + rr) * C + c0 + c];
  __syncthreads();
  const int kk = tid & 63, n4 = tid >> 6;
  for (int nn = n4; nn < 64; nn += 4)
    dst[(size_t)(row_off + c0 + nn) * 1024 + k0 + kk] = f2bf(t[nn][kk]);
}

// ---------------- 64x64-tile BK=64 GEMM, SPLIT-K x2, single-buf LDS ----------------
// 2x blocks (6/CU for qkv) halves per-block latency chain, doubles CU-level overlap.
// Partial fp32 written to pout[kh * M*N + row*N + col]; reduce kernel sums.
// bid in [0, 2*ntile): kh = bid >= ntile. XCD swizzle within each half.
__global__ __launch_bounds__(256) void gemm_sk_kernel(
    const ushort_t* __restrict__ A, const ushort_t* __restrict__ Bt, int ntile, int ntn, int N,
    float* __restrict__ pout)
{
  __shared__ __align__(16) ushort_t lA[64 * 64];
  __shared__ __align__(16) ushort_t lB[64 * 64];
  int bid = blockIdx.x;
  const int kh = bid >= ntile ? 1 : 0;
  bid -= kh * ntile;
  const int xcd = bid & 7, g = bid >> 3;
  const int m0 = (xcd + 8 * (g / ntn)) * 64;
  const int n0 = (g % ntn) * 64;
  const int ks = kh * 512;

  const int tid = threadIdx.x;
  const int lane = tid & 63, w = tid >> 6;
  const int quad = lane >> 4, l16 = lane & 15;
  const int rw = (w >> 1) * 32, cw = (w & 1) * 32;

  // staging: LDS(row, pos) holds global chunk (pos ^ (row&7)); swizzle source addr
  const int rs = tid >> 3;
  const int swz = (tid & 7) ^ (rs & 7);
  const int eL = tid * 8;
  const ushort_t* Ab = A + (size_t)(m0 + rs) * 1024 + swz * 8;
  const ushort_t* Bb = Bt + (size_t)(n0 + rs) * 1024 + swz * 8;

  const int xa = l16 & 7;
  f32x4 acc[2][2] = {};

  for (int k0 = ks; k0 < ks + 512; k0 += 64) {
    __syncthreads();
    __builtin_amdgcn_global_load_lds(
        (const __attribute__((address_space(1))) unsigned int*)(Ab + k0),
        (__attribute__((address_space(3))) unsigned int*)(lA + eL), 16, 0, 0);
    __builtin_amdgcn_global_load_lds(
        (const __attribute__((address_space(1))) unsigned int*)(Ab + 32 * 1024 + k0),
        (__attribute__((address_space(3))) unsigned int*)(lA + eL + 2048), 16, 0, 0);
    __builtin_amdgcn_global_load_lds(
        (const __attribute__((address_space(1))) unsigned int*)(Bb + k0),
        (__attribute__((address_space(3))) unsigned int*)(lB + eL), 16, 0, 0);
    __builtin_amdgcn_global_load_lds(
        (const __attribute__((address_space(1))) unsigned int*)(Bb + 32 * 1024 + k0),
        (__attribute__((address_space(3))) unsigned int*)(lB + eL + 2048), 16, 0, 0);
    __syncthreads();

#pragma unroll
    for (int khh = 0; khh < 2; ++khh) {
      bf16x8 a0 = *(const bf16x8*)(lA + (rw + l16) * 64      + (((khh * 4 + quad) ^ xa) << 3));
      bf16x8 a1 = *(const bf16x8*)(lA + (rw + 16 + l16) * 64 + (((khh * 4 + quad) ^ xa) << 3));
      bf16x8 b0 = *(const bf16x8*)(lB + (cw + l16) * 64      + (((khh * 4 + quad) ^ xa) << 3));
      bf16x8 b1 = *(const bf16x8*)(lB + (cw + 16 + l16) * 64 + (((khh * 4 + quad) ^ xa) << 3));
      acc[0][0] = __builtin_amdgcn_mfma_f32_16x16x32_bf16(a0, b0, acc[0][0], 0, 0, 0);
      acc[0][1] = __builtin_amdgcn_mfma_f32_16x16x32_bf16(a0, b1, acc[0][1], 0, 0, 0);
      acc[1][0] = __builtin_amdgcn_mfma_f32_16x16x32_bf16(a1, b0, acc[1][0], 0, 0, 0);
      acc[1][1] = __builtin_amdgcn_mfma_f32_16x16x32_bf16(a1, b1, acc[1][1], 0, 0, 0);
    }
  }

  float* po = pout + (size_t)kh * 2048 * N;
#pragma unroll
  for (int mg = 0; mg < 2; ++mg)
#pragma unroll
    for (int ng = 0; ng < 2; ++ng)
#pragma unroll
      for (int r = 0; r < 4; ++r) {
        const int row = m0 + rw + mg * 16 + quad * 4 + r;
        const int col = n0 + cw + ng * 16 + l16;
        po[(size_t)row * N + col] = acc[mg][ng][r];
      }
}

// ---------------- qkv reduce: sum 2 fp32 partials [2048][1536] -> bf16 q/k/v ----------------
__global__ __launch_bounds__(192) void qkv_reduce_kernel(
    const float* __restrict__ p, ushort_t* __restrict__ qout,
    ushort_t* __restrict__ kout, ushort_t* __restrict__ vout)
{
  const int row = blockIdx.x;
  const int col = blockIdx.y * 768 + threadIdx.x * 4;
  const size_t idx = (size_t)row * 1536 + col;
  float4 a = *(const float4*)(p + idx);
  float4 b = *(const float4*)(p + 2048 * 1536 + idx);
  ushortx4 o = { f2bf(a.x + b.x), f2bf(a.y + b.y), f2bf(a.z + b.z), f2bf(a.w + b.w) };
  if (col < 1024)      *(ushortx4*)(qout + (size_t)row * 1024 + col) = o;
  else if (col < 1280) *(ushortx4*)(kout + (size_t)row * 256 + (col - 1024)) = o;
  else                 *(ushortx4*)(vout + (size_t)row * 256 + (col - 1280)) = o;
}

// ---------------- out reduce: sum 2 fp32 partials [2048][1024] -> fp32 out ----------------
__global__ __launch_bounds__(256) void out_reduce_kernel(
    const float* __restrict__ p, float* __restrict__ out)
{
  const size_t idx = ((size_t)blockIdx.x * 256 + threadIdx.x) * 4;
  float4 a = *(const float4*)(p + idx);
  float4 b = *(const float4*)(p + 2048 * 1024 + idx);
  float4 o = { a.x + b.x, a.y + b.y, a.z + b.z, a.w + b.w };
  *(float4*)(out + idx) = o;
}

// ---------------- MFMA attention: block = (head, 64-query tile) ----------------
__global__ __launch_bounds__(256) void attn_mfma_kernel(
    const ushort_t* __restrict__ Q, const ushort_t* __restrict__ Kb,
    const ushort_t* __restrict__ Vb, ushort_t* __restrict__ O)
{
  __shared__ __align__(16) ushort_t lK[128 * 64];
  __shared__ __align__(16) ushort_t lVt[64 * 128];
  __shared__ __align__(16) ushort_t lKg[32 * 64];
  __shared__ __align__(16) ushort_t lVtg[64 * 40];
  __shared__ __align__(16) ushort_t lP[64 * 128];
  __shared__ __align__(16) ushort_t lPg[64 * 40];

  const int h = blockIdx.x, qb = blockIdx.y;
  const int tid = threadIdx.x;
  const int kvcol = (h >> 2) * 64;
  const int kbase = qb * 64 - 64;

  for (int cidx = tid; cidx < 1024; cidx += 256) {
    const int key = cidx >> 3, ch = cidx & 7;
    const int kpos = kbase + key;
    ushortx8 kv = {0,0,0,0,0,0,0,0}, vv = {0,0,0,0,0,0,0,0};
    if (kpos >= 0) {
      kv = *(const ushortx8*)(Kb + (size_t)kpos * 256 + kvcol + ch * 8);
      vv = *(const ushortx8*)(Vb + (size_t)kpos * 256 + kvcol + ch * 8);
    }
    *(ushortx8*)(lK + key * 64 + ((ch ^ (key & 7)) << 3)) = kv;
    const int kc = key >> 3, ke = key & 7;
#pragma unroll
    for (int e = 0; e < 8; ++e) {
      int dim = ch * 8 + e;
      lVt[dim * 128 + ((kc ^ (dim & 7)) << 3) + ke] = vv[e];
    }
  }
  {
    const int gk = tid >> 3, ch = tid & 7;
    const int kpos = gk * 64;
    ushortx8 kv = *(const ushortx8*)(Kb + (size_t)kpos * 256 + kvcol + ch * 8);
    ushortx8 vv = *(const ushortx8*)(Vb + (size_t)kpos * 256 + kvcol + ch * 8);
    *(ushortx8*)(lKg + gk * 64 + ((ch ^ (gk & 7)) << 3)) = kv;
#pragma unroll
    for (int e = 0; e < 8; ++e) lVtg[(ch * 8 + e) * 40 + gk] = vv[e];
  }
  __syncthreads();

  const int lane = tid & 63, w = tid >> 6;
  const int quad = lane >> 4, l16 = lane & 15;
  const int l7 = l16 & 7;
  const float slope = exp2f(-0.5f * (float)(h + 1));

  const int qrow = qb * 64 + w * 16 + l16;
  const ushort_t* qptr = Q + (size_t)qrow * 1024 + h * 64 + quad * 8;
  const bf16x8 aq0 = *(const bf16x8*)(qptr);
  const bf16x8 aq1 = *(const bf16x8*)(qptr + 32);

  float s[8][4];
#pragma unroll
  for (int kt = 0; kt < 8; ++kt) {
    const int key = kt * 16 + l16;
    const bf16x8 b0 = *(const bf16x8*)(lK + key * 64 + ((quad ^ l7) << 3));
    const bf16x8 b1 = *(const bf16x8*)(lK + key * 64 + (((4 + quad) ^ l7) << 3));
    f32x4 acc = {0.f, 0.f, 0.f, 0.f};
    acc = __builtin_amdgcn_mfma_f32_16x16x32_bf16(aq0, b0, acc, 0, 0, 0);
    acc = __builtin_amdgcn_mfma_f32_16x16x32_bf16(aq1, b1, acc, 0, 0, 0);
    const int kpos = kbase + key;
#pragma unroll
    for (int r = 0; r < 4; ++r) {
      const int qp = qb * 64 + w * 16 + quad * 4 + r;
      const int d = kpos - qp;
      const bool ok = (d <= 0) && (d >= -64) && (kpos >= 0);
      s[kt][r] = ok ? acc[r] * SCALE + (float)d * slope : -1e30f;
    }
  }
  float mr[4] = {-1e30f, -1e30f, -1e30f, -1e30f};
#pragma unroll
  for (int kt = 0; kt < 8; ++kt)
#pragma unroll
    for (int r = 0; r < 4; ++r) mr[r] = fmaxf(mr[r], s[kt][r]);
#pragma unroll
  for (int r = 0; r < 4; ++r) {
    mr[r] = fmaxf(mr[r], __shfl_xor(mr[r], 1));
    mr[r] = fmaxf(mr[r], __shfl_xor(mr[r], 2));
    mr[r] = fmaxf(mr[r], __shfl_xor(mr[r], 4));
    mr[r] = fmaxf(mr[r], __shfl_xor(mr[r], 8));
  }
  float lr[4] = {0.f, 0.f, 0.f, 0.f};
#pragma unroll
  for (int kt = 0; kt < 8; ++kt)
#pragma unroll
    for (int r = 0; r < 4; ++r) { float p = __expf(s[kt][r] - mr[r]); s[kt][r] = p; lr[r] += p; }
#pragma unroll
  for (int r = 0; r < 4; ++r) {
    lr[r] += __shfl_xor(lr[r], 1);
    lr[r] += __shfl_xor(lr[r], 2);
    lr[r] += __shfl_xor(lr[r], 4);
    lr[r] += __shfl_xor(lr[r], 8);
    lr[r] = 1.f / lr[r];
  }
#pragma unroll
  for (int kt = 0; kt < 8; ++kt) {
    const int kc = kt * 2 + (l16 >> 3);
#pragma unroll
    for (int r = 0; r < 4; ++r) {
      const int qr = w * 16 + quad * 4 + r;
      lP[qr * 128 + ((kc ^ (qr & 7)) << 3) + l7] = f2bf(s[kt][r] * lr[r]);
    }
  }

  float sg[2][4];
#pragma unroll
  for (int g16 = 0; g16 < 2; ++g16) {
    const int key = g16 * 16 + l16;
    const bf16x8 b0 = *(const bf16x8*)(lKg + key * 64 + ((quad ^ l7) << 3));
    const bf16x8 b1 = *(const bf16x8*)(lKg + key * 64 + (((4 + quad) ^ l7) << 3));
    f32x4 acc = {0.f, 0.f, 0.f, 0.f};
    acc = __builtin_amdgcn_mfma_f32_16x16x32_bf16(aq0, b0, acc, 0, 0, 0);
    acc = __builtin_amdgcn_mfma_f32_16x16x32_bf16(aq1, b1, acc, 0, 0, 0);
#pragma unroll
    for (int r = 0; r < 4; ++r) sg[g16][r] = acc[r] * SCALE;
  }
  float mg[4], lg[4];
#pragma unroll
  for (int r = 0; r < 4; ++r) {
    mg[r] = fmaxf(sg[0][r], sg[1][r]);
    mg[r] = fmaxf(mg[r], __shfl_xor(mg[r], 1));
    mg[r] = fmaxf(mg[r], __shfl_xor(mg[r], 2));
    mg[r] = fmaxf(mg[r], __shfl_xor(mg[r], 4));
    mg[r] = fmaxf(mg[r], __shfl_xor(mg[r], 8));
  }
#pragma unroll
  for (int r = 0; r < 4; ++r) {
    float p0 = __expf(sg[0][r] - mg[r]);
    float p1 = __expf(sg[1][r] - mg[r]);
    sg[0][r] = p0; sg[1][r] = p1;
    lg[r] = p0 + p1;
    lg[r] += __shfl_xor(lg[r], 1);
    lg[r] += __shfl_xor(lg[r], 2);
    lg[r] += __shfl_xor(lg[r], 4);
    lg[r] += __shfl_xor(lg[r], 8);
    lg[r] = 1.f / lg[r];
  }
#pragma unroll
  for (int g16 = 0; g16 < 2; ++g16)
#pragma unroll
    for (int r = 0; r < 4; ++r) {
      const int qr = w * 16 + quad * 4 + r;
      lPg[qr * 40 + g16 * 16 + l16] = f2bf(sg[g16][r] * lg[r]);
    }

  f32x4 acco[4] = {};
  const int qA = w * 16 + l16;
#pragma unroll
  for (int kki = 0; kki < 4; ++kki) {
    const bf16x8 ap = *(const bf16x8*)(lP + qA * 128 + (((kki * 4 + quad) ^ l7) << 3));
#pragma unroll
    for (int nt = 0; nt < 4; ++nt) {
      const int dim = nt * 16 + l16;
      const bf16x8 bv = *(const bf16x8*)(lVt + dim * 128 + (((kki * 4 + quad) ^ l7) << 3));
      acco[nt] = __builtin_amdgcn_mfma_f32_16x16x32_bf16(ap, bv, acco[nt], 0, 0, 0);
    }
  }
  {
    const bf16x8 apg = *(const bf16x8*)(lPg + qA * 40 + quad * 8);
#pragma unroll
    for (int nt = 0; nt < 4; ++nt) {
      const bf16x8 bvg = *(const bf16x8*)(lVtg + (nt * 16 + l16) * 40 + quad * 8);
      acco[nt] = __builtin_amdgcn_mfma_f32_16x16x32_bf16(apg, bvg, acco[nt], 0, 0, 0);
    }
  }
#pragma unroll
  for (int nt = 0; nt < 4; ++nt)
#pragma unroll
    for (int r = 0; r < 4; ++r) {
      const int qp = qb * 64 + w * 16 + quad * 4 + r;
      O[(size_t)qp * 1024 + h * 64 + nt * 16 + l16] = f2bf(acco[nt][r]);
    }
}

extern "C" void kernel_launch(void* const* d_in, const int* in_sizes, int n_in,
                              void* d_out, int out_size, void* d_ws, size_t ws_size,
                              hipStream_t stream)
{
  const float* x  = (const float*)d_in[0];
  const float* Wq = (const float*)d_in[1];
  const float* Wk = (const float*)d_in[2];
  const float* Wv = (const float*)d_in[3];
  const float* Wo = (const float*)d_in[4];
  float* out = (float*)d_out;

  char* ws = (char*)d_ws;
  ushort_t* x_bf   = (ushort_t*)(ws);                        // 4 MB   [2048][1024]
  ushort_t* wqkv_t = (ushort_t*)(ws + (4ull  << 20));        // 3 MB   [1536][1024]
  ushort_t* wo_t   = (ushort_t*)(ws + (7ull  << 20));        // 2 MB   [1024][1024]
  ushort_t* q_bf   = (ushort_t*)(ws + (9ull  << 20));        // 4 MB   [2048][1024]
  ushort_t* k_bf   = (ushort_t*)(ws + (13ull << 20));        // 1 MB   [2048][256]
  ushort_t* v_bf   = (ushort_t*)(ws + (14ull << 20));        // 1 MB   [2048][256]
  ushort_t* at_bf  = (ushort_t*)(ws + (15ull << 20));        // 4 MB   [2048][1024]
  float*    pqkv   = (float*)(ws + (20ull << 20));           // 25.2 MB [2][2048][1536]
  float*    pout   = (float*)(ws + (48ull << 20));           // 16.8 MB [2][2048][1024]

  prep_kernel<<<2688, 256, 0, stream>>>(x, Wq, Wk, Wv, Wo, x_bf, wqkv_t, wo_t);
  // qkv: 32 m-tiles x 24 n-tiles = 768 tiles x 2 K-halves = 1536 blocks (6/CU)
  gemm_sk_kernel<<<1536, 256, 0, stream>>>(x_bf, wqkv_t, 768, 24, 1536, pqkv);
  qkv_reduce_kernel<<<dim3(2048, 2), 192, 0, stream>>>(pqkv, q_bf, k_bf, v_bf);
  attn_mfma_kernel<<<dim3(16, 32), 256, 0, stream>>>(q_bf, k_bf, v_bf, at_bf);
  // out: 32 m-tiles x 16 n-tiles = 512 tiles x 2 K-halves = 1024 blocks (4/CU)
  gemm_sk_kernel<<<1024, 256, 0, stream>>>(at_bf, wo_t, 512, 16, 1024, pout);
  out_reduce_kernel<<<2048, 256, 0, stream>>>(pout, out);
}

// Round 8
// 105.865 us; speedup vs baseline: 1.0965x; 1.0965x over previous
//
#include <hip/hip_runtime.h>

#define SCALE 0.125f

typedef unsigned short ushort_t;
typedef unsigned short ushortx8 __attribute__((ext_vector_type(8)));
typedef unsigned short ushortx4 __attribute__((ext_vector_type(4)));
typedef short bf16x8 __attribute__((ext_vector_type(8)));
typedef float f32x4 __attribute__((ext_vector_type(4)));

__device__ inline ushort_t f2bf(float f) {
  unsigned int u = __float_as_uint(f);
  u += 0x7FFFu + ((u >> 16) & 1u);
  return (ushort_t)(u >> 16);
}
__device__ inline float bf2f(ushort_t u) {
  return __uint_as_float(((unsigned int)u) << 16);
}

// ---------------- fused prep: x cvt + 4 weight transposes ----------------
__global__ __launch_bounds__(256) void prep_kernel(
    const float* __restrict__ x, const float* __restrict__ Wq, const float* __restrict__ Wk,
    const float* __restrict__ Wv, const float* __restrict__ Wo,
    ushort_t* __restrict__ x_bf, ushort_t* __restrict__ wqkv_t, ushort_t* __restrict__ wo_t)
{
  __shared__ float t[64][65];
  int bid = blockIdx.x;
  const int tid = threadIdx.x;
  if (bid < 2048) {
    int idx = (bid * 256 + tid) * 4;
    if (idx < 2048 * 1024) {
      float4 f = *(const float4*)(x + idx);
      ushortx4 o = { f2bf(f.x), f2bf(f.y), f2bf(f.z), f2bf(f.w) };
      *(ushortx4*)(x_bf + idx) = o;
    }
    return;
  }
  bid -= 2048;
  const float* src; int C; ushort_t* dst; int row_off, cb, kb;
  if (bid < 256)      { src = Wq; C = 1024; dst = wqkv_t; row_off = 0;    cb = bid & 15; kb = bid >> 4; }
  else if (bid < 320) { int j = bid - 256; src = Wk; C = 256; dst = wqkv_t; row_off = 1024; cb = j & 3; kb = j >> 2; }
  else if (bid < 384) { int j = bid - 320; src = Wv; C = 256; dst = wqkv_t; row_off = 1280; cb = j & 3; kb = j >> 2; }
  else                { int j = bid - 384; src = Wo; C = 1024; dst = wo_t; row_off = 0;    cb = j & 15; kb = j >> 4; }
  const int c0 = cb * 64, k0 = kb * 64;
  const int c = tid & 63, r4 = tid >> 6;
  for (int rr = r4; rr < 64; rr += 4)
    t[c][rr] = src[(size_t)(k0 + rr) * C + c0 + c];
  __syncthreads();
  const int kk = tid & 63, n4 = tid >> 6;
  for (int nn = n4; nn < 64; nn += 4)
    dst[(size_t)(row_off + c0 + nn) * 1024 + k0 + kk] = f2bf(t[nn][kk]);
}

// ---------------- 64x64-tile BK=128 GEMM: 8 iterations (halved latency chain) ----------------
// LDS 32 KB single-buf -> 5 blocks/CU capacity. xor-16 swizzle: LDS(row,pos) holds
// global chunk (pos ^ (row&15)); frag rows all have row&15 == l16 -> read pos = c ^ l16.
// C[M][N] = A[M][1024] * Bt[N][1024]^T. bid = g*8 + xcd.
// mode 0: split bf16 out to q/k/v. mode 1: fp32 out [.][1024].
__global__ __launch_bounds__(256) void gemm128_kernel(
    const ushort_t* __restrict__ A, const ushort_t* __restrict__ Bt, int mode, int ntn,
    ushort_t* __restrict__ qout, ushort_t* __restrict__ kout, ushort_t* __restrict__ vout,
    float* __restrict__ fout)
{
  __shared__ __align__(16) ushort_t lA[64 * 128];   // 16 KB
  __shared__ __align__(16) ushort_t lB[64 * 128];   // 16 KB
  const int bid = blockIdx.x;
  const int xcd = bid & 7, g = bid >> 3;
  const int m0 = (xcd + 8 * (g / ntn)) * 64;
  const int n0 = (g % ntn) * 64;

  const int tid = threadIdx.x;
  const int lane = tid & 63, w = tid >> 6;
  const int quad = lane >> 4, l16 = lane & 15;
  const int rw = (w >> 1) * 32, cw = (w & 1) * 32;

  // staging: 64 rows x 256B; thread t covers (row = t>>4, pos = t&15), 4 rounds of +16 rows.
  // (rs+16k)&15 == rs&15 -> one swizzle for all rounds. LDS dst = tid*16B + round*4KB (linear).
  const int rs = tid >> 4;
  const int ps = tid & 15;
  const int swz = ps ^ (rs & 15);
  const int eL = tid * 8;                        // ushort elems
  const ushort_t* Ab = A + (size_t)(m0 + rs) * 1024 + swz * 8;
  const ushort_t* Bb = Bt + (size_t)(n0 + rs) * 1024 + swz * 8;

  f32x4 acc[2][2] = {};

  for (int k0 = 0; k0 < 1024; k0 += 128) {
    __syncthreads();
#pragma unroll
    for (int rd = 0; rd < 4; ++rd) {
      __builtin_amdgcn_global_load_lds(
          (const __attribute__((address_space(1))) unsigned int*)(Ab + (size_t)rd * 16 * 1024 + k0),
          (__attribute__((address_space(3))) unsigned int*)(lA + eL + rd * 2048), 16, 0, 0);
      __builtin_amdgcn_global_load_lds(
          (const __attribute__((address_space(1))) unsigned int*)(Bb + (size_t)rd * 16 * 1024 + k0),
          (__attribute__((address_space(3))) unsigned int*)(lB + eL + rd * 2048), 16, 0, 0);
    }
    __syncthreads();

#pragma unroll
    for (int kh = 0; kh < 4; ++kh) {
      const int ca = ((kh * 4 + quad) ^ l16) << 3;
      bf16x8 a0 = *(const bf16x8*)(lA + (rw + l16) * 128      + ca);
      bf16x8 a1 = *(const bf16x8*)(lA + (rw + 16 + l16) * 128 + ca);
      bf16x8 b0 = *(const bf16x8*)(lB + (cw + l16) * 128      + ca);
      bf16x8 b1 = *(const bf16x8*)(lB + (cw + 16 + l16) * 128 + ca);
      acc[0][0] = __builtin_amdgcn_mfma_f32_16x16x32_bf16(a0, b0, acc[0][0], 0, 0, 0);
      acc[0][1] = __builtin_amdgcn_mfma_f32_16x16x32_bf16(a0, b1, acc[0][1], 0, 0, 0);
      acc[1][0] = __builtin_amdgcn_mfma_f32_16x16x32_bf16(a1, b0, acc[1][0], 0, 0, 0);
      acc[1][1] = __builtin_amdgcn_mfma_f32_16x16x32_bf16(a1, b1, acc[1][1], 0, 0, 0);
    }
  }

#pragma unroll
  for (int mg = 0; mg < 2; ++mg)
#pragma unroll
    for (int ng = 0; ng < 2; ++ng)
#pragma unroll
      for (int r = 0; r < 4; ++r) {
        const int row = m0 + rw + mg * 16 + quad * 4 + r;
        const int col = n0 + cw + ng * 16 + l16;
        const float v = acc[mg][ng][r];
        if (mode == 0) {
          if (n0 < 1024)       qout[(size_t)row * 1024 + col] = f2bf(v);
          else if (n0 < 1280)  kout[(size_t)row * 256 + (col - 1024)] = f2bf(v);
          else                 vout[(size_t)row * 256 + (col - 1280)] = f2bf(v);
        } else {
          fout[(size_t)row * 1024 + col] = v;
        }
      }
}

// ---------------- MFMA attention: block = (head, 64-query tile) ----------------
__global__ __launch_bounds__(256) void attn_mfma_kernel(
    const ushort_t* __restrict__ Q, const ushort_t* __restrict__ Kb,
    const ushort_t* __restrict__ Vb, ushort_t* __restrict__ O)
{
  __shared__ __align__(16) ushort_t lK[128 * 64];
  __shared__ __align__(16) ushort_t lVt[64 * 128];
  __shared__ __align__(16) ushort_t lKg[32 * 64];
  __shared__ __align__(16) ushort_t lVtg[64 * 40];
  __shared__ __align__(16) ushort_t lP[64 * 128];
  __shared__ __align__(16) ushort_t lPg[64 * 40];

  const int h = blockIdx.x, qb = blockIdx.y;
  const int tid = threadIdx.x;
  const int kvcol = (h >> 2) * 64;
  const int kbase = qb * 64 - 64;

  for (int cidx = tid; cidx < 1024; cidx += 256) {
    const int key = cidx >> 3, ch = cidx & 7;
    const int kpos = kbase + key;
    ushortx8 kv = {0,0,0,0,0,0,0,0}, vv = {0,0,0,0,0,0,0,0};
    if (kpos >= 0) {
      kv = *(const ushortx8*)(Kb + (size_t)kpos * 256 + kvcol + ch * 8);
      vv = *(const ushortx8*)(Vb + (size_t)kpos * 256 + kvcol + ch * 8);
    }
    *(ushortx8*)(lK + key * 64 + ((ch ^ (key & 7)) << 3)) = kv;
    const int kc = key >> 3, ke = key & 7;
#pragma unroll
    for (int e = 0; e < 8; ++e) {
      int dim = ch * 8 + e;
      lVt[dim * 128 + ((kc ^ (dim & 7)) << 3) + ke] = vv[e];
    }
  }
  {
    const int gk = tid >> 3, ch = tid & 7;
    const int kpos = gk * 64;
    ushortx8 kv = *(const ushortx8*)(Kb + (size_t)kpos * 256 + kvcol + ch * 8);
    ushortx8 vv = *(const ushortx8*)(Vb + (size_t)kpos * 256 + kvcol + ch * 8);
    *(ushortx8*)(lKg + gk * 64 + ((ch ^ (gk & 7)) << 3)) = kv;
#pragma unroll
    for (int e = 0; e < 8; ++e) lVtg[(ch * 8 + e) * 40 + gk] = vv[e];
  }
  __syncthreads();

  const int lane = tid & 63, w = tid >> 6;
  const int quad = lane >> 4, l16 = lane & 15;
  const int l7 = l16 & 7;
  const float slope = exp2f(-0.5f * (float)(h + 1));

  const int qrow = qb * 64 + w * 16 + l16;
  const ushort_t* qptr = Q + (size_t)qrow * 1024 + h * 64 + quad * 8;
  const bf16x8 aq0 = *(const bf16x8*)(qptr);
  const bf16x8 aq1 = *(const bf16x8*)(qptr + 32);

  float s[8][4];
#pragma unroll
  for (int kt = 0; kt < 8; ++kt) {
    const int key = kt * 16 + l16;
    const bf16x8 b0 = *(const bf16x8*)(lK + key * 64 + ((quad ^ l7) << 3));
    const bf16x8 b1 = *(const bf16x8*)(lK + key * 64 + (((4 + quad) ^ l7) << 3));
    f32x4 acc = {0.f, 0.f, 0.f, 0.f};
    acc = __builtin_amdgcn_mfma_f32_16x16x32_bf16(aq0, b0, acc, 0, 0, 0);
    acc = __builtin_amdgcn_mfma_f32_16x16x32_bf16(aq1, b1, acc, 0, 0, 0);
    const int kpos = kbase + key;
#pragma unroll
    for (int r = 0; r < 4; ++r) {
      const int qp = qb * 64 + w * 16 + quad * 4 + r;
      const int d = kpos - qp;
      const bool ok = (d <= 0) && (d >= -64) && (kpos >= 0);
      s[kt][r] = ok ? acc[r] * SCALE + (float)d * slope : -1e30f;
    }
  }
  float mr[4] = {-1e30f, -1e30f, -1e30f, -1e30f};
#pragma unroll
  for (int kt = 0; kt < 8; ++kt)
#pragma unroll
    for (int r = 0; r < 4; ++r) mr[r] = fmaxf(mr[r], s[kt][r]);
#pragma unroll
  for (int r = 0; r < 4; ++r) {
    mr[r] = fmaxf(mr[r], __shfl_xor(mr[r], 1));
    mr[r] = fmaxf(mr[r], __shfl_xor(mr[r], 2));
    mr[r] = fmaxf(mr[r], __shfl_xor(mr[r], 4));
    mr[r] = fmaxf(mr[r], __shfl_xor(mr[r], 8));
  }
  float lr[4] = {0.f, 0.f, 0.f, 0.f};
#pragma unroll
  for (int kt = 0; kt < 8; ++kt)
#pragma unroll
    for (int r = 0; r < 4; ++r) { float p = __expf(s[kt][r] - mr[r]); s[kt][r] = p; lr[r] += p; }
#pragma unroll
  for (int r = 0; r < 4; ++r) {
    lr[r] += __shfl_xor(lr[r], 1);
    lr[r] += __shfl_xor(lr[r], 2);
    lr[r] += __shfl_xor(lr[r], 4);
    lr[r] += __shfl_xor(lr[r], 8);
    lr[r] = 1.f / lr[r];
  }
#pragma unroll
  for (int kt = 0; kt < 8; ++kt) {
    const int kc = kt * 2 + (l16 >> 3);
#pragma unroll
    for (int r = 0; r < 4; ++r) {
      const int qr = w * 16 + quad * 4 + r;
      lP[qr * 128 + ((kc ^ (qr & 7)) << 3) + l7] = f2bf(s[kt][r] * lr[r]);
    }
  }

  float sg[2][4];
#pragma unroll
  for (int g16 = 0; g16 < 2; ++g16) {
    const int key = g16 * 16 + l16;
    const bf16x8 b0 = *(const bf16x8*)(lKg + key * 64 + ((quad ^ l7) << 3));
    const bf16x8 b1 = *(const bf16x8*)(lKg + key * 64 + (((4 + quad) ^ l7) << 3));
    f32x4 acc = {0.f, 0.f, 0.f, 0.f};
    acc = __builtin_amdgcn_mfma_f32_16x16x32_bf16(aq0, b0, acc, 0, 0, 0);
    acc = __builtin_amdgcn_mfma_f32_16x16x32_bf16(aq1, b1, acc, 0, 0, 0);
#pragma unroll
    for (int r = 0; r < 4; ++r) sg[g16][r] = acc[r] * SCALE;
  }
  float mg[4], lg[4];
#pragma unroll
  for (int r = 0; r < 4; ++r) {
    mg[r] = fmaxf(sg[0][r], sg[1][r]);
    mg[r] = fmaxf(mg[r], __shfl_xor(mg[r], 1));
    mg[r] = fmaxf(mg[r], __shfl_xor(mg[r], 2));
    mg[r] = fmaxf(mg[r], __shfl_xor(mg[r], 4));
    mg[r] = fmaxf(mg[r], __shfl_xor(mg[r], 8));
  }
#pragma unroll
  for (int r = 0; r < 4; ++r) {
    float p0 = __expf(sg[0][r] - mg[r]);
    float p1 = __expf(sg[1][r] - mg[r]);
    sg[0][r] = p0; sg[1][r] = p1;
    lg[r] = p0 + p1;
    lg[r] += __shfl_xor(lg[r], 1);
    lg[r] += __shfl_xor(lg[r], 2);
    lg[r] += __shfl_xor(lg[r], 4);
    lg[r] += __shfl_xor(lg[r], 8);
    lg[r] = 1.f / lg[r];
  }
#pragma unroll
  for (int g16 = 0; g16 < 2; ++g16)
#pragma unroll
    for (int r = 0; r < 4; ++r) {
      const int qr = w * 16 + quad * 4 + r;
      lPg[qr * 40 + g16 * 16 + l16] = f2bf(sg[g16][r] * lg[r]);
    }

  f32x4 acco[4] = {};
  const int qA = w * 16 + l16;
#pragma unroll
  for (int kki = 0; kki < 4; ++kki) {
    const bf16x8 ap = *(const bf16x8*)(lP + qA * 128 + (((kki * 4 + quad) ^ l7) << 3));
#pragma unroll
    for (int nt = 0; nt < 4; ++nt) {
      const int dim = nt * 16 + l16;
      const bf16x8 bv = *(const bf16x8*)(lVt + dim * 128 + (((kki * 4 + quad) ^ l7) << 3));
      acco[nt] = __builtin_amdgcn_mfma_f32_16x16x32_bf16(ap, bv, acco[nt], 0, 0, 0);
    }
  }
  {
    const bf16x8 apg = *(const bf16x8*)(lPg + qA * 40 + quad * 8);
#pragma unroll
    for (int nt = 0; nt < 4; ++nt) {
      const bf16x8 bvg = *(const bf16x8*)(lVtg + (nt * 16 + l16) * 40 + quad * 8);
      acco[nt] = __builtin_amdgcn_mfma_f32_16x16x32_bf16(apg, bvg, acco[nt], 0, 0, 0);
    }
  }
#pragma unroll
  for (int nt = 0; nt < 4; ++nt)
#pragma unroll
    for (int r = 0; r < 4; ++r) {
      const int qp = qb * 64 + w * 16 + quad * 4 + r;
      O[(size_t)qp * 1024 + h * 64 + nt * 16 + l16] = f2bf(acco[nt][r]);
    }
}

extern "C" void kernel_launch(void* const* d_in, const int* in_sizes, int n_in,
                              void* d_out, int out_size, void* d_ws, size_t ws_size,
                              hipStream_t stream)
{
  const float* x  = (const float*)d_in[0];
  const float* Wq = (const float*)d_in[1];
  const float* Wk = (const float*)d_in[2];
  const float* Wv = (const float*)d_in[3];
  const float* Wo = (const float*)d_in[4];
  float* out = (float*)d_out;

  char* ws = (char*)d_ws;
  ushort_t* x_bf   = (ushort_t*)(ws);                        // 4 MB   [2048][1024]
  ushort_t* wqkv_t = (ushort_t*)(ws + (4ull  << 20));        // 3 MB   [1536][1024]
  ushort_t* wo_t   = (ushort_t*)(ws + (7ull  << 20));        // 2 MB   [1024][1024]
  ushort_t* q_bf   = (ushort_t*)(ws + (9ull  << 20));        // 4 MB   [2048][1024]
  ushort_t* k_bf   = (ushort_t*)(ws + (13ull << 20));        // 1 MB   [2048][256]
  ushort_t* v_bf   = (ushort_t*)(ws + (14ull << 20));        // 1 MB   [2048][256]
  ushort_t* at_bf  = (ushort_t*)(ws + (15ull << 20));        // 4 MB   [2048][1024]

  prep_kernel<<<2688, 256, 0, stream>>>(x, Wq, Wk, Wv, Wo, x_bf, wqkv_t, wo_t);
  // qkv: 32 m-tiles x 24 n-tiles = 768 blocks (3/CU), 8 K-iterations each
  gemm128_kernel<<<768, 256, 0, stream>>>(x_bf, wqkv_t, 0, 24, q_bf, k_bf, v_bf, nullptr);
  attn_mfma_kernel<<<dim3(16, 32), 256, 0, stream>>>(q_bf, k_bf, v_bf, at_bf);
  // out: 32 m-tiles x 16 n-tiles = 512 blocks (2/CU), 8 K-iterations each
  gemm128_kernel<<<512, 256, 0, stream>>>(at_bf, wo_t, 1, 16, nullptr, nullptr, nullptr, out);
}